// Round 1
// baseline (45.651 us; speedup 1.0000x reference)
//
#include <hip/hip_runtime.h>

// RulesLoss: B=1024, T=8192
//   g[i] = gap1(tok[i], d[i]) + gap2(tok[i], d[i], d[i+1], i<T-1)
//   rules[i] = d[i] - g[i] + g[i+1]   (g[T] := 0)
//   out = 0.6 * mean( (log(d+1) - log(rules+1))^2 )
// Single pass, memory-bound (64 MB read). Deterministic 2-stage reduction.

constexpr int TT = 8192;
constexpr int BB = 1024;
constexpr int NBLK = 2048;          // 2 blocks per row, 4096 elems each
constexpr float LOSS_SCALE = 0.6f;

__device__ __forceinline__ float gapf(float d, float dn, int t, bool hn) {
    // gap1: token in {94,122,100,92,43,27}, expected {2,3,2,2,5,5}
    float e = ((t == 94) | (t == 100) | (t == 92)) ? 2.0f
            : (t == 122) ? 3.0f
            : ((t == 43) | (t == 27)) ? 5.0f
            : 0.0f;
    bool in1 = (t == 94) | (t == 122) | (t == 100) | (t == 92) | (t == 43) | (t == 27);
    float g = (in1 && (d > e)) ? (d - e) : 0.0f;
    // gap2: token in {44,28,29,27,121,43}
    bool in2 = (t == 44) | (t == 28) | (t == 29) | (t == 27) | (t == 121) | (t == 43);
    if (in2 && hn && (3.0f * d > dn)) g += d - dn * (1.0f / 3.0f);
    return g;
}

__global__ __launch_bounds__(256) void rules_partial(const float* __restrict__ dur,
                                                     const int* __restrict__ tok,
                                                     float* __restrict__ partial) {
    int blk = blockIdx.x;            // 0..2047
    int row = blk >> 1;
    int half = blk & 1;
    const float* dr = dur + (size_t)row * TT;
    const int*   tr = tok + (size_t)row * TT;
    int v0 = half * 1024;            // float4-index base within row

    float acc = 0.0f;
#pragma unroll
    for (int k = 0; k < 4; ++k) {
        int v = v0 + (int)threadIdx.x + k * 256;   // coalesced across threads
        int i0 = v * 4;                            // row-local element index
        float4 d = *reinterpret_cast<const float4*>(dr + i0);
        int4   t = *reinterpret_cast<const int4*>(tr + i0);

        bool more = (i0 + 4) < TT;                 // halo exists
        float d4 = 0.0f, d5 = 0.0f;
        int   t4 = 0;
        if (more) {
            float2 dd = *reinterpret_cast<const float2*>(dr + i0 + 4);
            d4 = dd.x; d5 = dd.y;                  // i0+5 <= 8189 whenever more
            t4 = tr[i0 + 4];
        }

        float g0 = gapf(d.x, d.y, t.x, true);
        float g1 = gapf(d.y, d.z, t.y, true);
        float g2 = gapf(d.z, d.w, t.z, true);
        float g3 = gapf(d.w, d4,  t.w, more);      // pos i0+3: has_next iff i0+4 < T
        float g4 = more ? gapf(d4, d5, t4, true) : 0.0f;  // g[T] := 0 at row end

        float ds[4] = {d.x, d.y, d.z, d.w};
        float gs[5] = {g0, g1, g2, g3, g4};
#pragma unroll
        for (int j = 0; j < 4; ++j) {
            float dp1 = ds[j] + 1.0f;
            float num = ds[j] - gs[j] + gs[j + 1] + 1.0f;  // rules + 1
            // If gs[j]==gs[j+1]==0, num == dp1 bit-exact -> ratio exactly 1 -> log exactly 0.
            float c = __logf(__fdividef(num, dp1));        // = -(a-b); squared below
            acc = fmaf(c, c, acc);
        }
    }

    // wave + block reduce
#pragma unroll
    for (int off = 32; off; off >>= 1) acc += __shfl_down(acc, off, 64);
    __shared__ float sred[4];
    int lane = threadIdx.x & 63, wid = threadIdx.x >> 6;
    if (lane == 0) sred[wid] = acc;
    __syncthreads();
    if (threadIdx.x == 0) partial[blk] = sred[0] + sred[1] + sred[2] + sred[3];
}

__global__ __launch_bounds__(256) void rules_final(const float* __restrict__ partial,
                                                   float* __restrict__ out) {
    float acc = 0.0f;
    for (int i = threadIdx.x; i < NBLK; i += 256) acc += partial[i];
#pragma unroll
    for (int off = 32; off; off >>= 1) acc += __shfl_down(acc, off, 64);
    __shared__ float sred[4];
    int lane = threadIdx.x & 63, wid = threadIdx.x >> 6;
    if (lane == 0) sred[wid] = acc;
    __syncthreads();
    if (threadIdx.x == 0) {
        float total = sred[0] + sred[1] + sred[2] + sred[3];
        out[0] = LOSS_SCALE * (total / (float)((long long)BB * TT));
    }
}

extern "C" void kernel_launch(void* const* d_in, const int* in_sizes, int n_in,
                              void* d_out, int out_size, void* d_ws, size_t ws_size,
                              hipStream_t stream) {
    const float* dur = (const float*)d_in[0];
    const int*   tok = (const int*)d_in[1];
    float* partial = (float*)d_ws;          // 2048 floats, fully rewritten each call
    float* out = (float*)d_out;

    rules_partial<<<NBLK, 256, 0, stream>>>(dur, tok, partial);
    rules_final<<<1, 256, 0, stream>>>(partial, out);
}

// Round 2
// 28.502 us; speedup vs baseline: 1.6016x; 1.6016x over previous
//
#include <hip/hip_runtime.h>

// RulesLoss: B=1024, T=8192
//   g[i] = gap1(tok[i], d[i]) + gap2(tok[i], d[i], d[i+1], i<T-1)
//   rules[i] = d[i] - g[i] + g[i+1]   (g beyond row end := 0)
//   out = 0.6 * mean( (log(d+1) - log(rules+1))^2 )
// Latency-bound fix: batch all loads up front, halo via __shfl_down (lane 63
// falls back to hoisted masked loads). Deterministic 2-stage reduction.

constexpr int TT = 8192;
constexpr int BB = 1024;
constexpr int NBLK = 2048;          // 2 blocks per row, 4096 elems each
constexpr float LOSS_SCALE = 0.6f;

__device__ __forceinline__ float gapf(float d, float dn, int t, bool hn) {
    // token-set membership via 128-bit masks (two u64 halves selected by t&64)
    // IV keys {94,122,100,92,43,27}: low bits {43,27}, high bits {30,58,36,28}
    const unsigned long long M1L = 0x0000080008000000ULL;
    const unsigned long long M1H = 0x0400001050000000ULL;
    // RATIO keys {44,28,29,27,121,43}: low bits {44,28,29,27,43}, high bit {57}
    const unsigned long long M2L = 0x0000180038000000ULL;
    const unsigned long long M2H = 0x0200000000000000ULL;
    bool hi = (t & 64) != 0;
    unsigned long long m1 = hi ? M1H : M1L;
    unsigned long long m2 = hi ? M2H : M2L;
    int s = t & 63;
    bool in1 = (m1 >> s) & 1ULL;
    bool in2 = (m2 >> s) & 1ULL;
    // expected value among IV keys: t<64 -> {43,27} -> 5; t==122 -> 3; else 2
    float e = hi ? ((t == 122) ? 3.0f : 2.0f) : 5.0f;
    float g = (in1 && (d > e)) ? (d - e) : 0.0f;
    if (in2 && hn && (3.0f * d > dn)) g += d - dn * (1.0f / 3.0f);
    return g;
}

__global__ __launch_bounds__(256) void rules_partial(const float* __restrict__ dur,
                                                     const int* __restrict__ tok,
                                                     float* __restrict__ partial) {
    int blk = blockIdx.x;            // 0..2047
    int row = blk >> 1;
    int half = blk & 1;
    const float* dr = dur + (size_t)row * TT;
    const int*   tr = tok + (size_t)row * TT;
    int tid = (int)threadIdx.x;
    int lane = tid & 63;
    int v0 = half * 1024;            // float4-index base within row

    // ---- batched loads: 8 dwordx4 in flight before any compute ----
    float4 d[4];
    int4   t[4];
    int    i0[4];
#pragma unroll
    for (int k = 0; k < 4; ++k) {
        int v = v0 + tid + k * 256;
        i0[k] = v * 4;
        d[k] = *reinterpret_cast<const float4*>(dr + i0[k]);
        t[k] = *reinterpret_cast<const int4*>(tr + i0[k]);
    }

    // ---- lane-63 halo (next chunk belongs to the next wave): masked loads,
    //      hoisted so they overlap with the main loads ----
    float hd0[4], hd1[4];
    int   ht[4];
    bool  hmore[4];
#pragma unroll
    for (int k = 0; k < 4; ++k) { hd0[k] = 0.0f; hd1[k] = 0.0f; ht[k] = 0; hmore[k] = true; }
    if (lane == 63) {
#pragma unroll
        for (int k = 0; k < 4; ++k) {
            int ih = i0[k] + 4;
            if (ih < TT) {
                float2 dd = *reinterpret_cast<const float2*>(dr + ih);
                hd0[k] = dd.x; hd1[k] = dd.y;
                ht[k] = tr[ih];
            } else {
                hmore[k] = false;   // last chunk of the row: g beyond row := 0
            }
        }
    }

    float acc = 0.0f;
#pragma unroll
    for (int k = 0; k < 4; ++k) {
        float d4 = __shfl_down(d[k].x, 1, 64);
        float d5 = __shfl_down(d[k].y, 1, 64);
        int   t4 = __shfl_down(t[k].x, 1, 64);
        bool more = true;
        if (lane == 63) { d4 = hd0[k]; d5 = hd1[k]; t4 = ht[k]; more = hmore[k]; }

        float g0 = gapf(d[k].x, d[k].y, t[k].x, true);
        float g1 = gapf(d[k].y, d[k].z, t[k].y, true);
        float g2 = gapf(d[k].z, d[k].w, t[k].z, true);
        float g3 = gapf(d[k].w, d4,     t[k].w, more); // pos i0+3: has_next iff i0+4 < T
        float g4 = more ? gapf(d4, d5, t4, true) : 0.0f;

        float ds[4] = {d[k].x, d[k].y, d[k].z, d[k].w};
        float gs[5] = {g0, g1, g2, g3, g4};
#pragma unroll
        for (int j = 0; j < 4; ++j) {
            float dp1 = ds[j] + 1.0f;
            float num = ds[j] - gs[j] + gs[j + 1] + 1.0f;  // rules + 1
            // gs both zero (>92% of elems) -> num bit-equal dp1 -> log is exactly 0
            float c = __logf(__fdividef(num, dp1));
            acc = fmaf(c, c, acc);
        }
    }

    // wave + block reduce
#pragma unroll
    for (int off = 32; off; off >>= 1) acc += __shfl_down(acc, off, 64);
    __shared__ float sred[4];
    int wid = tid >> 6;
    if (lane == 0) sred[wid] = acc;
    __syncthreads();
    if (tid == 0) partial[blk] = sred[0] + sred[1] + sred[2] + sred[3];
}

__global__ __launch_bounds__(256) void rules_final(const float* __restrict__ partial,
                                                   float* __restrict__ out) {
    float acc = 0.0f;
    for (int i = threadIdx.x; i < NBLK; i += 256) acc += partial[i];
#pragma unroll
    for (int off = 32; off; off >>= 1) acc += __shfl_down(acc, off, 64);
    __shared__ float sred[4];
    int lane = threadIdx.x & 63, wid = threadIdx.x >> 6;
    if (lane == 0) sred[wid] = acc;
    __syncthreads();
    if (threadIdx.x == 0) {
        float total = sred[0] + sred[1] + sred[2] + sred[3];
        out[0] = LOSS_SCALE * (total / (float)((long long)BB * TT));
    }
}

extern "C" void kernel_launch(void* const* d_in, const int* in_sizes, int n_in,
                              void* d_out, int out_size, void* d_ws, size_t ws_size,
                              hipStream_t stream) {
    const float* dur = (const float*)d_in[0];
    const int*   tok = (const int*)d_in[1];
    float* partial = (float*)d_ws;          // 2048 floats, fully rewritten each call
    float* out = (float*)d_out;

    rules_partial<<<NBLK, 256, 0, stream>>>(dur, tok, partial);
    rules_final<<<1, 256, 0, stream>>>(partial, out);
}

// Round 3
// 19.580 us; speedup vs baseline: 2.3315x; 1.4557x over previous
//
#include <hip/hip_runtime.h>
#include <math.h>

// RulesLoss: B=1024, T=8192
//   gap1 = max(d - e1[tok], 0)            (e1 = +INF for non-IV tokens)
//   gap2 = max(fma(dn, -1/3, d), 0) * m2[tok]   (m2 in {0,1}; dn=+INF at row end)
//   g = gap1 + gap2 ; rules[i] = d[i] - g[i] + g[i+1]
//   out = 0.6 * mean( (log((rules+1)/(d+1)))^2 )
// 8 contiguous elems/thread: one shfl for d[8], one for g[8]; lane-63 halo load.

constexpr int TT = 8192;
constexpr int BB = 1024;
constexpr int NBLK = 4096;          // 4 blocks/row, 2048 elems/block, 8/thread
constexpr float LOSS_SCALE = 0.6f;

__global__ __launch_bounds__(256) void rules_partial(const float* __restrict__ dur,
                                                     const int* __restrict__ tok,
                                                     float* __restrict__ partial) {
    __shared__ float2 lut[128];
    int tid = (int)threadIdx.x;
    if (tid < 128) {
        int t = tid;
        float e1 = INFINITY;                       // non-member: gap1 = max(d-INF,0)=0
        if (t == 94 || t == 100 || t == 92) e1 = 2.0f;
        else if (t == 122)                  e1 = 3.0f;
        else if (t == 43 || t == 27)        e1 = 5.0f;
        float m2 = (t == 44 || t == 28 || t == 29 || t == 27 || t == 121 || t == 43)
                 ? 1.0f : 0.0f;
        lut[t] = make_float2(e1, m2);
    }
    __syncthreads();

    int blk = blockIdx.x;
    int row = blk >> 2, q = blk & 3;
    const float* dr = dur + (size_t)row * TT;
    const int*   tr = tok + (size_t)row * TT;
    int i0 = q * 2048 + tid * 8;
    int lane = tid & 63;

    // ---- batched loads (4 dwordx4 in flight) ----
    float4 da = *reinterpret_cast<const float4*>(dr + i0);
    float4 db = *reinterpret_cast<const float4*>(dr + i0 + 4);
    int4   ta = *reinterpret_cast<const int4*>(tr + i0);
    int4   tb = *reinterpret_cast<const int4*>(tr + i0 + 4);

    // lane-63 halo: next 2 durs + 1 token (masked; overlaps with main loads)
    bool rowend = (q == 3) && (tid == 255);
    float hd8 = 0.0f, hd9 = 0.0f; int ht8 = 0;
    if (lane == 63 && !rowend) {
        float2 hh = *reinterpret_cast<const float2*>(dr + i0 + 8);
        hd8 = hh.x; hd9 = hh.y;
        ht8 = tr[i0 + 8];
    }

    float d[9];
    d[0]=da.x; d[1]=da.y; d[2]=da.z; d[3]=da.w;
    d[4]=db.x; d[5]=db.y; d[6]=db.z; d[7]=db.w;
    int tk[8] = {ta.x, ta.y, ta.z, ta.w, tb.x, tb.y, tb.z, tb.w};

    // d[8] = neighbor's d[0]; lane63 from halo; row end -> +INF (kills g7.gap2)
    float d8s = __shfl_down(d[0], 1, 64);
    d[8] = (lane == 63) ? (rowend ? INFINITY : hd8) : d8s;

    float2 lm[8];
#pragma unroll
    for (int j = 0; j < 8; ++j) lm[j] = lut[tk[j] & 127];

    float g[9];
#pragma unroll
    for (int j = 0; j < 8; ++j) {
        float gap1 = fmaxf(d[j] - lm[j].x, 0.0f);
        float gap2 = fmaxf(fmaf(d[j+1], -(1.0f/3.0f), d[j]), 0.0f) * lm[j].y;
        g[j] = gap1 + gap2;
    }

    // g[8] = neighbor's g[0]; lane63 computes from halo; row end -> 0
    float g8s = __shfl_down(g[0], 1, 64);
    if (lane == 63) {
        float2 hlm = lut[ht8 & 127];
        float gap1 = fmaxf(hd8 - hlm.x, 0.0f);
        float gap2 = fmaxf(fmaf(hd9, -(1.0f/3.0f), hd8), 0.0f) * hlm.y;
        g8s = rowend ? 0.0f : (gap1 + gap2);
    }
    g[8] = g8s;

    float acc = 0.0f;
#pragma unroll
    for (int j = 0; j < 8; ++j) {
        float dp1 = d[j] + 1.0f;
        float num = d[j] - g[j] + g[j + 1] + 1.0f;   // rules + 1
        float c = __logf(__fdividef(num, dp1));      // 0 when both gaps are 0
        acc = fmaf(c, c, acc);
    }

    // wave + block reduce
#pragma unroll
    for (int off = 32; off; off >>= 1) acc += __shfl_down(acc, off, 64);
    __shared__ float sred[4];
    int wid = tid >> 6;
    if (lane == 0) sred[wid] = acc;
    __syncthreads();
    if (tid == 0) partial[blk] = sred[0] + sred[1] + sred[2] + sred[3];
}

__global__ __launch_bounds__(1024) void rules_final(const float* __restrict__ partial,
                                                    float* __restrict__ out) {
    float acc = 0.0f;
    for (int i = (int)threadIdx.x; i < NBLK; i += 1024) acc += partial[i];
#pragma unroll
    for (int off = 32; off; off >>= 1) acc += __shfl_down(acc, off, 64);
    __shared__ float sred[16];
    int lane = threadIdx.x & 63, wid = threadIdx.x >> 6;
    if (lane == 0) sred[wid] = acc;
    __syncthreads();
    if (threadIdx.x == 0) {
        float total = 0.0f;
#pragma unroll
        for (int w = 0; w < 16; ++w) total += sred[w];
        out[0] = LOSS_SCALE * (total / (float)((long long)BB * TT));
    }
}

extern "C" void kernel_launch(void* const* d_in, const int* in_sizes, int n_in,
                              void* d_out, int out_size, void* d_ws, size_t ws_size,
                              hipStream_t stream) {
    const float* dur = (const float*)d_in[0];
    const int*   tok = (const int*)d_in[1];
    float* partial = (float*)d_ws;          // 4096 floats, fully rewritten each call
    float* out = (float*)d_out;

    rules_partial<<<NBLK, 256, 0, stream>>>(dur, tok, partial);
    rules_final<<<1, 1024, 0, stream>>>(partial, out);
}